// Round 6
// baseline (2564.577 us; speedup 1.0000x reference)
//
#include <hip/hip_runtime.h>
#include <hip/hip_bf16.h>

#define N_NODES 50000
#define N_EDGES 1600000
#define F_IN    128
#define F_OUT   8
#define K_TAPS  4
#define MAX_POWER 25     // F_OUT*(K_TAPS-1)+1

#define BROWS   64       // rows per bucket
#define NB      782      // ceil(N_NODES / BROWS)
#define CHUNK   4096     // edges per partition block
#define NPART   391      // ceil(N_EDGES / CHUNK)
#define ECAP    2816     // per-bucket slot capacity (mean 2048, sigma ~45 -> +17 sigma)

__device__ inline int wave_incl_scan(int v, int lane) {
    #pragma unroll
    for (int off = 1; off < 64; off <<= 1) {
        int t = __shfl_up(v, off, 64);
        if (lane >= off) v += t;
    }
    return v;
}

// ---------------------------------------------------------------------------
// Partition edges into fixed-stride bucket slots [b*ECAP, b*ECAP+cnt[b]).
// LDS staging -> semi-coalesced run writes. Payload: ((row&63)<<16)|col, val.
// ---------------------------------------------------------------------------
__global__ void partition_kernel(const int* __restrict__ rows,
                                 const int* __restrict__ cols,
                                 const float* __restrict__ vals,
                                 int* __restrict__ gcnt,
                                 int2* __restrict__ edges, int n_edges) {
    __shared__ int lhist[NB];
    __shared__ int lcur[NB];
    __shared__ int lbase[NB];
    __shared__ int2 stage[CHUNK];
    __shared__ unsigned short sbkt[CHUNK];
    __shared__ int wsum[4];
    int tid = threadIdx.x;
    int base = blockIdx.x * CHUNK;
    int cend = min(base + CHUNK, n_edges);

    for (int b = tid; b < NB; b += 256) lhist[b] = 0;
    __syncthreads();
    for (int i = base + tid; i < cend; i += 256)
        atomicAdd(&lhist[rows[i] >> 6], 1);
    __syncthreads();

    // exclusive scan of lhist -> lcur (block-local offsets)
    int lane = tid & 63, wid = tid >> 6;
    int b0 = tid * 4;
    int h[4]; int tsum = 0;
    #pragma unroll
    for (int j = 0; j < 4; ++j) {
        h[j] = (b0 + j < NB) ? lhist[b0 + j] : 0;
        tsum += h[j];
    }
    int incl = wave_incl_scan(tsum, lane);
    if (lane == 63) wsum[wid] = incl;
    __syncthreads();
    int woff = 0;
    for (int w = 0; w < wid; ++w) woff += wsum[w];
    int excl = woff + incl - tsum;
    #pragma unroll
    for (int j = 0; j < 4; ++j) {
        if (b0 + j < NB) lcur[b0 + j] = excl;
        excl += h[j];
    }
    __syncthreads();

    // reserve per-bucket global space (fixed stride, atomic count)
    for (int b = tid; b < NB; b += 256) {
        int c = lhist[b];
        if (c) {
            int g = atomicAdd(&gcnt[b], c);
            lbase[b] = b * ECAP + g - lcur[b];
        }
    }
    __syncthreads();

    // stage edges grouped-by-bucket in LDS
    for (int i = base + tid; i < cend; i += 256) {
        int r = rows[i], c = cols[i];
        float v = vals[i];
        int b = r >> 6;
        int pos = atomicAdd(&lcur[b], 1);
        stage[pos] = make_int2(((r & 63) << 16) | c, __float_as_int(v));
        sbkt[pos] = (unsigned short)b;
    }
    __syncthreads();

    // write out: consecutive staged slots -> consecutive global slots per run
    int cn = cend - base;
    for (int i = tid; i < cn; i += 256) {
        int b = sbkt[i];
        int o = lbase[b] + i;
        if (o - b * ECAP < ECAP)            // safety clamp (never hit for seed-0 data)
            edges[o] = stage[i];
    }
}

// ---------------------------------------------------------------------------
// Lean grid barrier: 8 arrival counters -> master -> monotone generation.
// Per-iteration counter slots (no reset races). s_sleep(2) spin (~128 cyc).
// ---------------------------------------------------------------------------
__device__ inline void gbar(int it, int b,
                            int* __restrict__ bar_cnt,
                            int* __restrict__ bar_master,
                            int* __restrict__ bar_gen) {
    __syncthreads();
    if (threadIdx.x == 0) {
        __threadfence();                               // release: dst visible device-wide
        int r = b & 7;
        int need = (NB >> 3) + (r < (NB & 7) ? 1 : 0); // 98 for r<6 else 97 (sums to 782)
        int c = __hip_atomic_fetch_add(&bar_cnt[it * 8 + r], 1,
                                       __ATOMIC_ACQ_REL, __HIP_MEMORY_SCOPE_AGENT);
        if (c == need - 1) {
            int m = __hip_atomic_fetch_add(&bar_master[it], 1,
                                           __ATOMIC_ACQ_REL, __HIP_MEMORY_SCOPE_AGENT);
            if (m == 7)
                __hip_atomic_store(bar_gen, it + 1,
                                   __ATOMIC_RELEASE, __HIP_MEMORY_SCOPE_AGENT);
        }
        while (__hip_atomic_load(bar_gen, __ATOMIC_ACQUIRE,
                                 __HIP_MEMORY_SCOPE_AGENT) < it + 1)
            __builtin_amdgcn_s_sleep(2);
        __threadfence();                               // acquire: drop stale lines
    }
    __syncthreads();
}

// ---------------------------------------------------------------------------
// Persistent cooperative chain: rowsum + 25 SpMV hops + y-fold.
// One block per bucket; edges cached in LDS once; custom barrier between hops.
// ---------------------------------------------------------------------------
__global__ __launch_bounds__(256, 4)
void chain_kernel(const int* __restrict__ gcnt,
                  const int2* __restrict__ edges,
                  const float* __restrict__ x,
                  const float* __restrict__ coeff,
                  float* __restrict__ u,
                  float* __restrict__ buf0,
                  float* __restrict__ buf1,
                  float* __restrict__ y,
                  int* __restrict__ bar_cnt,
                  int* __restrict__ bar_master,
                  int* __restrict__ bar_gen,
                  int n_nodes) {
    __shared__ int2  ecache[ECAP];
    __shared__ float acc[BROWS];
    __shared__ float yacc[BROWS * F_OUT];
    __shared__ float lcoeff[F_OUT * K_TAPS];

    int tid = threadIdx.x;
    int b = blockIdx.x;

    if (tid < BROWS) acc[tid] = 0.f;
    for (int j = tid; j < BROWS * F_OUT; j += 256) yacc[j] = 0.f;
    if (tid < F_OUT * K_TAPS) lcoeff[tid] = coeff[tid];

    // cache this bucket's edge slice in LDS (reused 25x)
    int cnt = min(gcnt[b], ECAP);
    const int2* eb = edges + (size_t)b * ECAP;
    for (int i = tid; i < cnt; i += 256) ecache[i] = eb[i];

    // rowsum: u[n] = sum_f x[n,f]  (grid-stride, one wave per node)
    {
        int lane = tid & 63;
        int wave = (b * 256 + tid) >> 6;
        int n_waves = NB * 4;
        for (int node = wave; node < n_nodes; node += n_waves) {
            const float2* xp = (const float2*)(x + (size_t)node * F_IN);
            float2 v = xp[lane];
            float s = v.x + v.y;
            #pragma unroll
            for (int off = 32; off > 0; off >>= 1)
                s += __shfl_down(s, off, 64);
            if (lane == 0) u[node] = s;
        }
    }
    gbar(0, b, bar_cnt, bar_master, bar_gen);          // u visible everywhere

    for (int p = 0; p < MAX_POWER; ++p) {
        const float* src = (p == 0) ? u : ((p & 1) ? buf0 : buf1);
        float* dst = (p & 1) ? buf1 : buf0;

        for (int i = tid; i < cnt; i += 256) {
            int2 ev = ecache[i];
            atomicAdd(&acc[ev.x >> 16], __int_as_float(ev.y) * src[ev.x & 0xFFFF]);
        }
        __syncthreads();

        if (tid < BROWS) {
            int row = b * BROWS + tid;
            float val = acc[tid];
            acc[tid] = 0.f;
            if (p < MAX_POWER - 1 && row < n_nodes) dst[row] = val;
            // fold into y: power index p feeds output o at tap k = p - 3o
            #pragma unroll
            for (int o = 0; o < F_OUT; ++o) {
                int k = p - (K_TAPS - 1) * o;
                if (k >= 0 && k < K_TAPS)
                    yacc[tid * F_OUT + o] += lcoeff[o * K_TAPS + k] * val;
            }
        }
        if (p < MAX_POWER - 1)
            gbar(p + 1, b, bar_cnt, bar_master, bar_gen);
    }

    __syncthreads();
    for (int j = tid; j < BROWS * F_OUT; j += 256) {
        int row = b * BROWS + (j >> 3);
        if (row < n_nodes) y[(size_t)row * F_OUT + (j & 7)] = yacc[j];
    }
}

extern "C" void kernel_launch(void* const* d_in, const int* in_sizes, int n_in,
                              void* d_out, int out_size, void* d_ws, size_t ws_size,
                              hipStream_t stream) {
    const float* x        = (const float*)d_in[0];
    const int*   gso_rows = (const int*)d_in[1];
    const int*   gso_cols = (const int*)d_in[2];
    const float* gso_vals = (const float*)d_in[3];
    const float* coeff    = (const float*)d_in[4];
    float* y = (float*)d_out;

    // ws layout: u[N] | buf0[N] | buf1[N] | edges[NB*ECAP] int2
    //            | gcnt[NB] | bar_cnt[26*8] | bar_master[26] | bar_gen[1]
    float* u     = (float*)d_ws;
    float* buf0  = u + N_NODES;
    float* buf1  = buf0 + N_NODES;
    int2*  edges = (int2*)(buf1 + N_NODES);            // byte off 600000, 8B-aligned
    int*   gcnt       = (int*)(edges + (size_t)NB * ECAP);
    int*   bar_cnt    = gcnt + NB;
    int*   bar_master = bar_cnt + 26 * 8;
    int*   bar_gen    = bar_master + 26;

    // zero control area (gcnt + all barrier state) in one memset
    hipMemsetAsync(gcnt, 0, (size_t)(NB + 26 * 8 + 26 + 1) * sizeof(int), stream);

    // bucket partition (fixed-stride slots; no scan needed)
    partition_kernel<<<NPART, 256, 0, stream>>>(
        gso_rows, gso_cols, gso_vals, gcnt, edges, N_EDGES);

    // fused persistent chain with lean custom barrier
    int n_nodes = N_NODES;
    void* args[] = { (void*)&gcnt, (void*)&edges, (void*)&x, (void*)&coeff,
                     (void*)&u, (void*)&buf0, (void*)&buf1, (void*)&y,
                     (void*)&bar_cnt, (void*)&bar_master, (void*)&bar_gen,
                     (void*)&n_nodes };
    hipLaunchCooperativeKernel((void*)chain_kernel, dim3(NB), dim3(256),
                               args, 0, stream);
}

// Round 7
// 629.613 us; speedup vs baseline: 4.0733x; 4.0733x over previous
//
#include <hip/hip_runtime.h>
#include <hip/hip_bf16.h>

#define N_NODES 50000
#define N_EDGES 1600000
#define F_IN    128
#define F_OUT   8
#define K_TAPS  4
#define MAX_POWER 25     // F_OUT*(K_TAPS-1)+1

#define BROWS   64       // rows per bucket
#define NB      782      // ceil(N_NODES / BROWS)
#define CHUNK   4096     // edges per partition block
#define NPART   391      // ceil(N_EDGES / CHUNK)
#define ECAP    2816     // per-bucket slot capacity (mean 2048, sigma ~45 -> +17 sigma)

__device__ inline int wave_incl_scan(int v, int lane) {
    #pragma unroll
    for (int off = 1; off < 64; off <<= 1) {
        int t = __shfl_up(v, off, 64);
        if (lane >= off) v += t;
    }
    return v;
}

// Coherent-point (L3) access helpers: relaxed agent-scope atomics compile to
// sc1 loads/stores that bypass the non-coherent per-XCD L2 and emit NO
// buffer_inv / buffer_wbl2 (that was R5/R6's 95us/hop storm).
__device__ inline float ld_coh(const float* p) {
    return __hip_atomic_load((float*)p, __ATOMIC_RELAXED, __HIP_MEMORY_SCOPE_AGENT);
}
__device__ inline void st_coh(float* p, float v) {
    __hip_atomic_store(p, v, __ATOMIC_RELAXED, __HIP_MEMORY_SCOPE_AGENT);
}

// ---------------------------------------------------------------------------
// Partition edges into fixed-stride bucket slots [b*ECAP, b*ECAP+cnt[b]).
// LDS staging -> semi-coalesced run writes. Payload: ((row&63)<<16)|col, val.
// ---------------------------------------------------------------------------
__global__ void partition_kernel(const int* __restrict__ rows,
                                 const int* __restrict__ cols,
                                 const float* __restrict__ vals,
                                 int* __restrict__ gcnt,
                                 int2* __restrict__ edges, int n_edges) {
    __shared__ int lhist[NB];
    __shared__ int lcur[NB];
    __shared__ int lbase[NB];
    __shared__ int2 stage[CHUNK];
    __shared__ unsigned short sbkt[CHUNK];
    __shared__ int wsum[4];
    int tid = threadIdx.x;
    int base = blockIdx.x * CHUNK;
    int cend = min(base + CHUNK, n_edges);

    for (int b = tid; b < NB; b += 256) lhist[b] = 0;
    __syncthreads();
    for (int i = base + tid; i < cend; i += 256)
        atomicAdd(&lhist[rows[i] >> 6], 1);
    __syncthreads();

    // exclusive scan of lhist -> lcur (block-local offsets)
    int lane = tid & 63, wid = tid >> 6;
    int b0 = tid * 4;
    int h[4]; int tsum = 0;
    #pragma unroll
    for (int j = 0; j < 4; ++j) {
        h[j] = (b0 + j < NB) ? lhist[b0 + j] : 0;
        tsum += h[j];
    }
    int incl = wave_incl_scan(tsum, lane);
    if (lane == 63) wsum[wid] = incl;
    __syncthreads();
    int woff = 0;
    for (int w = 0; w < wid; ++w) woff += wsum[w];
    int excl = woff + incl - tsum;
    #pragma unroll
    for (int j = 0; j < 4; ++j) {
        if (b0 + j < NB) lcur[b0 + j] = excl;
        excl += h[j];
    }
    __syncthreads();

    // reserve per-bucket global space (fixed stride, atomic count)
    for (int b = tid; b < NB; b += 256) {
        int c = lhist[b];
        if (c) {
            int g = atomicAdd(&gcnt[b], c);
            lbase[b] = b * ECAP + g - lcur[b];
        }
    }
    __syncthreads();

    // stage edges grouped-by-bucket in LDS
    for (int i = base + tid; i < cend; i += 256) {
        int r = rows[i], c = cols[i];
        float v = vals[i];
        int b = r >> 6;
        int pos = atomicAdd(&lcur[b], 1);
        stage[pos] = make_int2(((r & 63) << 16) | c, __float_as_int(v));
        sbkt[pos] = (unsigned short)b;
    }
    __syncthreads();

    // write out: consecutive staged slots -> consecutive global slots per run
    int cn = cend - base;
    for (int i = tid; i < cn; i += 256) {
        int b = sbkt[i];
        int o = lbase[b] + i;
        if (o - b * ECAP < ECAP)            // safety clamp (never hit for seed-0 data)
            edges[o] = stage[i];
    }
}

// ---------------------------------------------------------------------------
// Lean grid barrier, NO cache-maintenance: relaxed sc1 atomics only.
// __syncthreads() before arrival drains vmcnt(0), so all prior sc1 stores are
// L3-acked before the arrival add reaches L3 (happens-before at one endpoint).
// ---------------------------------------------------------------------------
__device__ inline void gbar(int it, int b,
                            int* __restrict__ bar_cnt,
                            int* __restrict__ bar_master,
                            int* __restrict__ bar_gen) {
    __syncthreads();
    if (threadIdx.x == 0) {
        int r = b & 7;
        int need = (NB >> 3) + (r < (NB & 7) ? 1 : 0);   // sums to 782
        int c = __hip_atomic_fetch_add(&bar_cnt[it * 8 + r], 1,
                                       __ATOMIC_RELAXED, __HIP_MEMORY_SCOPE_AGENT);
        if (c == need - 1) {
            int m = __hip_atomic_fetch_add(&bar_master[it], 1,
                                           __ATOMIC_RELAXED, __HIP_MEMORY_SCOPE_AGENT);
            if (m == 7)
                __hip_atomic_store(bar_gen, it + 1,
                                   __ATOMIC_RELAXED, __HIP_MEMORY_SCOPE_AGENT);
        }
        while (__hip_atomic_load(bar_gen, __ATOMIC_RELAXED,
                                 __HIP_MEMORY_SCOPE_AGENT) < it + 1)
            __builtin_amdgcn_s_sleep(4);                 // ~256-cyc poll interval
    }
    __syncthreads();
}

// ---------------------------------------------------------------------------
// Persistent cooperative chain: rowsum + 25 SpMV hops + y-fold.
// One block per bucket; edges cached in LDS once. All cross-hop vector
// traffic (u, buf0, buf1) goes through L3 via sc1 relaxed atomics.
// ---------------------------------------------------------------------------
__global__ __launch_bounds__(256, 4)
void chain_kernel(const int* __restrict__ gcnt,
                  const int2* __restrict__ edges,
                  const float* __restrict__ x,
                  const float* __restrict__ coeff,
                  float* __restrict__ u,
                  float* __restrict__ buf0,
                  float* __restrict__ buf1,
                  float* __restrict__ y,
                  int* __restrict__ bar_cnt,
                  int* __restrict__ bar_master,
                  int* __restrict__ bar_gen,
                  int n_nodes) {
    __shared__ int2  ecache[ECAP];
    __shared__ float acc[BROWS];
    __shared__ float yacc[BROWS * F_OUT];
    __shared__ float lcoeff[F_OUT * K_TAPS];

    int tid = threadIdx.x;
    int b = blockIdx.x;

    if (tid < BROWS) acc[tid] = 0.f;
    for (int j = tid; j < BROWS * F_OUT; j += 256) yacc[j] = 0.f;
    if (tid < F_OUT * K_TAPS) lcoeff[tid] = coeff[tid];

    // cache this bucket's edge slice in LDS (reused 25x); plain loads fine
    // (edges written by a previous dispatch -> kernel-boundary coherent)
    int cnt = min(gcnt[b], ECAP);
    const int2* eb = edges + (size_t)b * ECAP;
    for (int i = tid; i < cnt; i += 256) ecache[i] = eb[i];

    // rowsum: u[n] = sum_f x[n,f]; write-through so hop 0's sc1 gathers see it
    {
        int lane = tid & 63;
        int wave = (b * 256 + tid) >> 6;
        int n_waves = NB * 4;
        for (int node = wave; node < n_nodes; node += n_waves) {
            const float2* xp = (const float2*)(x + (size_t)node * F_IN);
            float2 v = xp[lane];
            float s = v.x + v.y;
            #pragma unroll
            for (int off = 32; off > 0; off >>= 1)
                s += __shfl_down(s, off, 64);
            if (lane == 0) st_coh(&u[node], s);
        }
    }
    gbar(0, b, bar_cnt, bar_master, bar_gen);

    for (int p = 0; p < MAX_POWER; ++p) {
        const float* src = (p == 0) ? u : ((p & 1) ? buf0 : buf1);
        float* dst = (p & 1) ? buf1 : buf0;

        for (int i = tid; i < cnt; i += 256) {
            int2 ev = ecache[i];
            float sv = ld_coh(&src[ev.x & 0xFFFF]);
            atomicAdd(&acc[ev.x >> 16], __int_as_float(ev.y) * sv);
        }
        __syncthreads();

        if (tid < BROWS) {
            int row = b * BROWS + tid;
            float val = acc[tid];
            acc[tid] = 0.f;
            if (p < MAX_POWER - 1 && row < n_nodes) st_coh(&dst[row], val);
            // fold into y: power index p feeds output o at tap k = p - 3o
            #pragma unroll
            for (int o = 0; o < F_OUT; ++o) {
                int k = p - (K_TAPS - 1) * o;
                if (k >= 0 && k < K_TAPS)
                    yacc[tid * F_OUT + o] += lcoeff[o * K_TAPS + k] * val;
            }
        }
        if (p < MAX_POWER - 1)
            gbar(p + 1, b, bar_cnt, bar_master, bar_gen);
    }

    __syncthreads();
    for (int j = tid; j < BROWS * F_OUT; j += 256) {
        int row = b * BROWS + (j >> 3);
        if (row < n_nodes) y[(size_t)row * F_OUT + (j & 7)] = yacc[j];
    }
}

extern "C" void kernel_launch(void* const* d_in, const int* in_sizes, int n_in,
                              void* d_out, int out_size, void* d_ws, size_t ws_size,
                              hipStream_t stream) {
    const float* x        = (const float*)d_in[0];
    const int*   gso_rows = (const int*)d_in[1];
    const int*   gso_cols = (const int*)d_in[2];
    const float* gso_vals = (const float*)d_in[3];
    const float* coeff    = (const float*)d_in[4];
    float* y = (float*)d_out;

    // ws layout: u[N] | buf0[N] | buf1[N] | edges[NB*ECAP] int2
    //            | gcnt[NB] | bar_cnt[26*8] | bar_master[26] | bar_gen[1]
    float* u     = (float*)d_ws;
    float* buf0  = u + N_NODES;
    float* buf1  = buf0 + N_NODES;
    int2*  edges = (int2*)(buf1 + N_NODES);            // byte off 600000, 8B-aligned
    int*   gcnt       = (int*)(edges + (size_t)NB * ECAP);
    int*   bar_cnt    = gcnt + NB;
    int*   bar_master = bar_cnt + 26 * 8;
    int*   bar_gen    = bar_master + 26;

    // zero control area (gcnt + all barrier state) in one memset
    hipMemsetAsync(gcnt, 0, (size_t)(NB + 26 * 8 + 26 + 1) * sizeof(int), stream);

    // bucket partition (fixed-stride slots; no scan needed)
    partition_kernel<<<NPART, 256, 0, stream>>>(
        gso_rows, gso_cols, gso_vals, gcnt, edges, N_EDGES);

    // fused persistent chain with fence-free sc1 barrier
    int n_nodes = N_NODES;
    void* args[] = { (void*)&gcnt, (void*)&edges, (void*)&x, (void*)&coeff,
                     (void*)&u, (void*)&buf0, (void*)&buf1, (void*)&y,
                     (void*)&bar_cnt, (void*)&bar_master, (void*)&bar_gen,
                     (void*)&n_nodes };
    hipLaunchCooperativeKernel((void*)chain_kernel, dim3(NB), dim3(256),
                               args, 0, stream);
}

// Round 8
// 476.386 us; speedup vs baseline: 5.3834x; 1.3216x over previous
//
#include <hip/hip_runtime.h>
#include <hip/hip_bf16.h>

#define N_NODES 50000
#define N_EDGES 1600000
#define F_IN    128
#define F_OUT   8
#define K_TAPS  4
#define MAX_POWER 25     // F_OUT*(K_TAPS-1)+1

#define BROWS   64       // rows per bucket
#define NB      782      // ceil(N_NODES / BROWS)
#define CHUNK   4096     // edges per partition block
#define NPART   391      // ceil(N_EDGES / CHUNK)
#define ECAP    2816     // per-bucket slot capacity (mean 2048, sigma ~45)

#define BAR_LINES 32     // arrival counter lines
#define LSTRIDE   32     // ints per counter line (128 B padding)

__device__ inline int wave_incl_scan(int v, int lane) {
    #pragma unroll
    for (int off = 1; off < 64; off <<= 1) {
        int t = __shfl_up(v, off, 64);
        if (lane >= off) v += t;
    }
    return v;
}

// sc1 store: goes to L3 (coherence point), bypassing non-coherent per-XCD L2.
__device__ inline void st_coh(float* p, float v) {
    __hip_atomic_store(p, v, __ATOMIC_RELAXED, __HIP_MEMORY_SCOPE_AGENT);
}

// ---------------------------------------------------------------------------
// Partition edges into fixed-stride bucket slots [b*ECAP, b*ECAP+cnt[b]).
// LDS staging -> semi-coalesced run writes. Payload: ((row&63)<<16)|col, val.
// ---------------------------------------------------------------------------
__global__ void partition_kernel(const int* __restrict__ rows,
                                 const int* __restrict__ cols,
                                 const float* __restrict__ vals,
                                 int* __restrict__ gcnt,
                                 int2* __restrict__ edges, int n_edges) {
    __shared__ int lhist[NB];
    __shared__ int lcur[NB];
    __shared__ int lbase[NB];
    __shared__ int2 stage[CHUNK];
    __shared__ unsigned short sbkt[CHUNK];
    __shared__ int wsum[4];
    int tid = threadIdx.x;
    int base = blockIdx.x * CHUNK;
    int cend = min(base + CHUNK, n_edges);

    for (int b = tid; b < NB; b += 256) lhist[b] = 0;
    __syncthreads();
    for (int i = base + tid; i < cend; i += 256)
        atomicAdd(&lhist[rows[i] >> 6], 1);
    __syncthreads();

    int lane = tid & 63, wid = tid >> 6;
    int b0 = tid * 4;
    int h[4]; int tsum = 0;
    #pragma unroll
    for (int j = 0; j < 4; ++j) {
        h[j] = (b0 + j < NB) ? lhist[b0 + j] : 0;
        tsum += h[j];
    }
    int incl = wave_incl_scan(tsum, lane);
    if (lane == 63) wsum[wid] = incl;
    __syncthreads();
    int woff = 0;
    for (int w = 0; w < wid; ++w) woff += wsum[w];
    int excl = woff + incl - tsum;
    #pragma unroll
    for (int j = 0; j < 4; ++j) {
        if (b0 + j < NB) lcur[b0 + j] = excl;
        excl += h[j];
    }
    __syncthreads();

    for (int b = tid; b < NB; b += 256) {
        int c = lhist[b];
        if (c) {
            int g = atomicAdd(&gcnt[b], c);
            lbase[b] = b * ECAP + g - lcur[b];
        }
    }
    __syncthreads();

    for (int i = base + tid; i < cend; i += 256) {
        int r = rows[i], c = cols[i];
        float v = vals[i];
        int b = r >> 6;
        int pos = atomicAdd(&lcur[b], 1);
        stage[pos] = make_int2(((r & 63) << 16) | c, __float_as_int(v));
        sbkt[pos] = (unsigned short)b;
    }
    __syncthreads();

    int cn = cend - base;
    for (int i = tid; i < cn; i += 256) {
        int b = sbkt[i];
        int o = lbase[b] + i;
        if (o - b * ECAP < ECAP)
            edges[o] = stage[i];
    }
}

// ---------------------------------------------------------------------------
// Lean grid barrier: 32 padded arrival lines -> master -> generation word.
// Relaxed sc1 atomics only (no buffer_inv/wbl2). __syncthreads() before
// arrival drains vmcnt(0) so prior sc1 stores are L3-acked; __syncthreads()
// after the spin is a full compiler barrier (no load hoisting).
// ---------------------------------------------------------------------------
__device__ inline void gbar(int it, int b,
                            int* __restrict__ bar_cnt,
                            int* __restrict__ bar_master,
                            int* __restrict__ bar_gen) {
    __syncthreads();
    if (threadIdx.x == 0) {
        int r = b & (BAR_LINES - 1);
        // NB = 782 = 32*24 + 14 -> lines 0..13 serve 25 blocks, rest 24
        int need = (NB / BAR_LINES) + (r < (NB % BAR_LINES) ? 1 : 0);
        int c = __hip_atomic_fetch_add(&bar_cnt[(it * BAR_LINES + r) * LSTRIDE], 1,
                                       __ATOMIC_RELAXED, __HIP_MEMORY_SCOPE_AGENT);
        if (c == need - 1) {
            int m = __hip_atomic_fetch_add(&bar_master[it * LSTRIDE], 1,
                                           __ATOMIC_RELAXED, __HIP_MEMORY_SCOPE_AGENT);
            if (m == BAR_LINES - 1)
                __hip_atomic_store(bar_gen, it + 1,
                                   __ATOMIC_RELAXED, __HIP_MEMORY_SCOPE_AGENT);
        }
        while (__hip_atomic_load(bar_gen, __ATOMIC_RELAXED,
                                 __HIP_MEMORY_SCOPE_AGENT) < it + 1)
            __builtin_amdgcn_s_sleep(2);
    }
    __syncthreads();
}

// ---------------------------------------------------------------------------
// Persistent chain: rowsum + 25 SpMV hops + y-fold.
// Fresh dst buffer per hop (single-writer-then-read) => readers may use
// PLAIN CACHED loads (L2-hit gathers); writers use sc1 stores to L3.
// ---------------------------------------------------------------------------
__global__ __launch_bounds__(256, 4)
void chain_kernel(const int* __restrict__ gcnt,
                  const int2* __restrict__ edges,
                  const float* __restrict__ x,
                  const float* __restrict__ coeff,
                  float* __restrict__ u,
                  float* __restrict__ s,          // 25 * N_NODES
                  float* __restrict__ y,
                  int* __restrict__ bar_cnt,
                  int* __restrict__ bar_master,
                  int* __restrict__ bar_gen,
                  int n_nodes) {
    __shared__ int2  ecache[ECAP];
    __shared__ float acc[BROWS];
    __shared__ float yacc[BROWS * F_OUT];
    __shared__ float lcoeff[F_OUT * K_TAPS];

    int tid = threadIdx.x;
    int b = blockIdx.x;

    if (tid < BROWS) acc[tid] = 0.f;
    for (int j = tid; j < BROWS * F_OUT; j += 256) yacc[j] = 0.f;
    if (tid < F_OUT * K_TAPS) lcoeff[tid] = coeff[tid];

    // cache this bucket's edge slice in LDS (reused 25x)
    int cnt = min(gcnt[b], ECAP);
    const int2* eb = edges + (size_t)b * ECAP;
    for (int i = tid; i < cnt; i += 256) ecache[i] = eb[i];

    // rowsum: u[n] = sum_f x[n,f]; sc1 store so hop 0 reads fresh from L3
    {
        int lane = tid & 63;
        int wave = (b * 256 + tid) >> 6;
        int n_waves = NB * 4;
        for (int node = wave; node < n_nodes; node += n_waves) {
            const float2* xp = (const float2*)(x + (size_t)node * F_IN);
            float2 v = xp[lane];
            float sm = v.x + v.y;
            #pragma unroll
            for (int off = 32; off > 0; off >>= 1)
                sm += __shfl_down(sm, off, 64);
            if (lane == 0) st_coh(&u[node], sm);
        }
    }
    gbar(0, b, bar_cnt, bar_master, bar_gen);

    for (int p = 0; p < MAX_POWER; ++p) {
        // src: buffer written at previous hop (complete before barrier p)
        const float* __restrict__ src = (p == 0) ? u : s + (size_t)(p - 1) * n_nodes;
        float* dst = s + (size_t)p * n_nodes;

        for (int i = tid; i < cnt; i += 256) {
            int2 ev = ecache[i];
            float sv = src[ev.x & 0xFFFF];           // plain load -> L2 cached
            atomicAdd(&acc[ev.x >> 16], __int_as_float(ev.y) * sv);
        }
        __syncthreads();

        if (tid < BROWS) {
            int row = b * BROWS + tid;
            float val = acc[tid];
            acc[tid] = 0.f;
            if (p < MAX_POWER - 1 && row < n_nodes) st_coh(&dst[row], val);
            #pragma unroll
            for (int o = 0; o < F_OUT; ++o) {
                int k = p - (K_TAPS - 1) * o;        // tap index for output o
                if (k >= 0 && k < K_TAPS)
                    yacc[tid * F_OUT + o] += lcoeff[o * K_TAPS + k] * val;
            }
        }
        if (p < MAX_POWER - 1)
            gbar(p + 1, b, bar_cnt, bar_master, bar_gen);
    }

    __syncthreads();
    for (int j = tid; j < BROWS * F_OUT; j += 256) {
        int row = b * BROWS + (j >> 3);
        if (row < n_nodes) y[(size_t)row * F_OUT + (j & 7)] = yacc[j];
    }
}

extern "C" void kernel_launch(void* const* d_in, const int* in_sizes, int n_in,
                              void* d_out, int out_size, void* d_ws, size_t ws_size,
                              hipStream_t stream) {
    const float* x        = (const float*)d_in[0];
    const int*   gso_rows = (const int*)d_in[1];
    const int*   gso_cols = (const int*)d_in[2];
    const float* gso_vals = (const float*)d_in[3];
    const float* coeff    = (const float*)d_in[4];
    float* y = (float*)d_out;

    // ws layout: u[N] | s[25N] | edges[NB*ECAP] int2 | gcnt[NB]
    //            | bar_cnt[25*32*32] | bar_master[25*32] | bar_gen[1]
    float* u     = (float*)d_ws;
    float* s     = u + N_NODES;
    int2*  edges = (int2*)(s + (size_t)MAX_POWER * N_NODES);  // 26*50000*4 B, 8B-aligned
    int*   gcnt       = (int*)(edges + (size_t)NB * ECAP);
    int*   bar_cnt    = gcnt + NB;
    int*   bar_master = bar_cnt + MAX_POWER * BAR_LINES * LSTRIDE;
    int*   bar_gen    = bar_master + MAX_POWER * LSTRIDE;

    // zero control area (gcnt + all barrier state) in one memset
    size_t ctrl_ints = (size_t)NB + MAX_POWER * BAR_LINES * LSTRIDE
                     + MAX_POWER * LSTRIDE + 1;
    hipMemsetAsync(gcnt, 0, ctrl_ints * sizeof(int), stream);

    // bucket partition (fixed-stride slots)
    partition_kernel<<<NPART, 256, 0, stream>>>(
        gso_rows, gso_cols, gso_vals, gcnt, edges, N_EDGES);

    // fused persistent chain
    int n_nodes = N_NODES;
    void* args[] = { (void*)&gcnt, (void*)&edges, (void*)&x, (void*)&coeff,
                     (void*)&u, (void*)&s, (void*)&y,
                     (void*)&bar_cnt, (void*)&bar_master, (void*)&bar_gen,
                     (void*)&n_nodes };
    hipLaunchCooperativeKernel((void*)chain_kernel, dim3(NB), dim3(256),
                               args, 0, stream);
}

// Round 9
// 424.749 us; speedup vs baseline: 6.0379x; 1.1216x over previous
//
#include <hip/hip_runtime.h>
#include <hip/hip_bf16.h>

#define N_NODES 50000
#define N_EDGES 1600000
#define F_IN    128
#define F_OUT   8
#define K_TAPS  4
#define MAX_POWER 25     // F_OUT*(K_TAPS-1)+1

#define NBLK    256      // chain blocks (1 per CU)
#define RPB     196      // rows per block (256*196 = 50176 >= 50000)
#define CHUNK   4096     // edges per partition block
#define NPART   391      // ceil(N_EDGES / CHUNK)
#define ECAP_G  8192     // global per-bucket slot stride (mean 6272, +24 sigma)
#define ECAP_L  6912     // LDS edge-cache capacity (mean 6272, +8 sigma)

#define BAR_LINES 16     // arrival counter lines (256/16 = 16 per line)
#define LSTRIDE   32     // ints per counter line (128 B padding)

__device__ inline int wave_incl_scan(int v, int lane) {
    #pragma unroll
    for (int off = 1; off < 64; off <<= 1) {
        int t = __shfl_up(v, off, 64);
        if (lane >= off) v += t;
    }
    return v;
}

// sc1 store: to L3 (coherence point), bypassing non-coherent per-XCD L2.
__device__ inline void st_coh(float* p, float v) {
    __hip_atomic_store(p, v, __ATOMIC_RELAXED, __HIP_MEMORY_SCOPE_AGENT);
}

// ---------------------------------------------------------------------------
// Partition edges into fixed-stride bucket slots (bucket = row / RPB).
// LDS staging -> semi-coalesced run writes. Payload: ((row%RPB)<<16)|col, val.
// ---------------------------------------------------------------------------
__global__ void partition_kernel(const int* __restrict__ rows,
                                 const int* __restrict__ cols,
                                 const float* __restrict__ vals,
                                 int* __restrict__ gcnt,
                                 int2* __restrict__ edges, int n_edges) {
    __shared__ int lhist[NBLK];
    __shared__ int lcur[NBLK];
    __shared__ int lbase[NBLK];
    __shared__ int2 stage[CHUNK];
    __shared__ unsigned char sbkt[CHUNK];
    __shared__ int wsum[4];
    int tid = threadIdx.x;
    int base = blockIdx.x * CHUNK;
    int cend = min(base + CHUNK, n_edges);

    lhist[tid] = 0;
    __syncthreads();
    for (int i = base + tid; i < cend; i += 256)
        atomicAdd(&lhist[rows[i] / RPB], 1);
    __syncthreads();

    // exclusive scan of lhist (one bucket per thread)
    int lane = tid & 63, wid = tid >> 6;
    int h = lhist[tid];
    int incl = wave_incl_scan(h, lane);
    if (lane == 63) wsum[wid] = incl;
    __syncthreads();
    int woff = 0;
    for (int w = 0; w < wid; ++w) woff += wsum[w];
    int excl = woff + incl - h;
    lcur[tid] = excl;
    // reserve global space for this bucket
    if (h) {
        int g = atomicAdd(&gcnt[tid], h);
        lbase[tid] = tid * ECAP_G + g - excl;
    }
    __syncthreads();

    // stage edges grouped-by-bucket in LDS
    for (int i = base + tid; i < cend; i += 256) {
        int r = rows[i], c = cols[i];
        float v = vals[i];
        int b = r / RPB;
        int pos = atomicAdd(&lcur[b], 1);
        stage[pos] = make_int2(((r - b * RPB) << 16) | c, __float_as_int(v));
        sbkt[pos] = (unsigned char)b;
    }
    __syncthreads();

    // write out: consecutive staged slots -> consecutive global slots per run
    int cn = cend - base;
    for (int i = tid; i < cn; i += 256) {
        int b = sbkt[i];
        int o = lbase[b] + i;
        if (o - b * ECAP_G < ECAP_G)       // safety clamp
            edges[o] = stage[i];
    }
}

// ---------------------------------------------------------------------------
// Lean grid barrier: 16 padded arrival lines -> master -> generation word.
// Relaxed sc1 atomics only (no buffer_inv/wbl2 — R6's 95us/hop storm).
// __syncthreads() before arrival drains vmcnt(0) => prior sc1 stores L3-acked.
// ---------------------------------------------------------------------------
__device__ inline void gbar(int it, int b,
                            int* __restrict__ bar_cnt,
                            int* __restrict__ bar_master,
                            int* __restrict__ bar_gen) {
    __syncthreads();
    if (threadIdx.x == 0) {
        int r = b & (BAR_LINES - 1);
        const int need = NBLK / BAR_LINES;       // exactly 16
        int c = __hip_atomic_fetch_add(&bar_cnt[(it * BAR_LINES + r) * LSTRIDE], 1,
                                       __ATOMIC_RELAXED, __HIP_MEMORY_SCOPE_AGENT);
        if (c == need - 1) {
            int m = __hip_atomic_fetch_add(&bar_master[it * LSTRIDE], 1,
                                           __ATOMIC_RELAXED, __HIP_MEMORY_SCOPE_AGENT);
            if (m == BAR_LINES - 1)
                __hip_atomic_store(bar_gen, it + 1,
                                   __ATOMIC_RELAXED, __HIP_MEMORY_SCOPE_AGENT);
        }
        while (__hip_atomic_load(bar_gen, __ATOMIC_RELAXED,
                                 __HIP_MEMORY_SCOPE_AGENT) < it + 1)
            __builtin_amdgcn_s_sleep(2);
    }
    __syncthreads();
}

// ---------------------------------------------------------------------------
// Persistent chain: rowsum + 25 SpMV hops + y-fold. 256 blocks x 512 threads.
// Fresh dst buffer per hop => readers use plain cached loads; writers sc1.
// ---------------------------------------------------------------------------
__global__ __launch_bounds__(512, 1)
void chain_kernel(const int* __restrict__ gcnt,
                  const int2* __restrict__ edges,
                  const float* __restrict__ x,
                  const float* __restrict__ coeff,
                  float* __restrict__ u,
                  float* __restrict__ s,          // 25 * N_NODES
                  float* __restrict__ y,
                  int* __restrict__ bar_cnt,
                  int* __restrict__ bar_master,
                  int* __restrict__ bar_gen,
                  int n_nodes) {
    __shared__ int2  ecache[ECAP_L];
    __shared__ float acc[RPB];
    __shared__ float yacc[RPB * F_OUT];
    __shared__ float lcoeff[F_OUT * K_TAPS];

    int tid = threadIdx.x;
    int b = blockIdx.x;

    if (tid < RPB) acc[tid] = 0.f;
    for (int j = tid; j < RPB * F_OUT; j += 512) yacc[j] = 0.f;
    if (tid < F_OUT * K_TAPS) lcoeff[tid] = coeff[tid];

    // cache this bucket's edge slice in LDS (reused 25x)
    int cnt = min(gcnt[b], ECAP_G);
    int cntl = min(cnt, ECAP_L);
    const int2* eb = edges + (size_t)b * ECAP_G;
    for (int i = tid; i < cntl; i += 512) ecache[i] = eb[i];

    // rowsum: u[n] = sum_f x[n,f]; sc1 store so hop 0 reads fresh
    {
        int lane = tid & 63;
        int wave = (b * 512 + tid) >> 6;
        int n_waves = NBLK * 8;
        for (int node = wave; node < n_nodes; node += n_waves) {
            const float2* xp = (const float2*)(x + (size_t)node * F_IN);
            float2 v = xp[lane];
            float sm = v.x + v.y;
            #pragma unroll
            for (int off = 32; off > 0; off >>= 1)
                sm += __shfl_down(sm, off, 64);
            if (lane == 0) st_coh(&u[node], sm);
        }
    }
    gbar(0, b, bar_cnt, bar_master, bar_gen);

    for (int p = 0; p < MAX_POWER; ++p) {
        const float* __restrict__ src = (p == 0) ? u : s + (size_t)(p - 1) * n_nodes;
        float* dst = s + (size_t)p * n_nodes;

        // 4-way unrolled gather: 4 independent src loads in flight
        int i = tid;
        for (; i + 3 * 512 < cntl; i += 4 * 512) {
            int2 e0 = ecache[i];
            int2 e1 = ecache[i + 512];
            int2 e2 = ecache[i + 1024];
            int2 e3 = ecache[i + 1536];
            float v0 = src[e0.x & 0xFFFF];
            float v1 = src[e1.x & 0xFFFF];
            float v2 = src[e2.x & 0xFFFF];
            float v3 = src[e3.x & 0xFFFF];
            atomicAdd(&acc[e0.x >> 16], __int_as_float(e0.y) * v0);
            atomicAdd(&acc[e1.x >> 16], __int_as_float(e1.y) * v1);
            atomicAdd(&acc[e2.x >> 16], __int_as_float(e2.y) * v2);
            atomicAdd(&acc[e3.x >> 16], __int_as_float(e3.y) * v3);
        }
        for (; i < cntl; i += 512) {
            int2 ev = ecache[i];
            atomicAdd(&acc[ev.x >> 16], __int_as_float(ev.y) * src[ev.x & 0xFFFF]);
        }
        for (int k = ECAP_L + tid; k < cnt; k += 512) {   // overflow (never for seed 0)
            int2 ev = eb[k];
            atomicAdd(&acc[ev.x >> 16], __int_as_float(ev.y) * src[ev.x & 0xFFFF]);
        }
        __syncthreads();

        if (tid < RPB) {
            int row = b * RPB + tid;
            float val = acc[tid];
            acc[tid] = 0.f;
            if (p < MAX_POWER - 1 && row < n_nodes) st_coh(&dst[row], val);
            #pragma unroll
            for (int o = 0; o < F_OUT; ++o) {
                int k = p - (K_TAPS - 1) * o;        // tap index for output o
                if (k >= 0 && k < K_TAPS)
                    yacc[tid * F_OUT + o] += lcoeff[o * K_TAPS + k] * val;
            }
        }
        if (p < MAX_POWER - 1)
            gbar(p + 1, b, bar_cnt, bar_master, bar_gen);
    }

    __syncthreads();
    for (int j = tid; j < RPB * F_OUT; j += 512) {
        int row = b * RPB + (j >> 3);
        if (row < n_nodes) y[(size_t)row * F_OUT + (j & 7)] = yacc[j];
    }
}

extern "C" void kernel_launch(void* const* d_in, const int* in_sizes, int n_in,
                              void* d_out, int out_size, void* d_ws, size_t ws_size,
                              hipStream_t stream) {
    const float* x        = (const float*)d_in[0];
    const int*   gso_rows = (const int*)d_in[1];
    const int*   gso_cols = (const int*)d_in[2];
    const float* gso_vals = (const float*)d_in[3];
    const float* coeff    = (const float*)d_in[4];
    float* y = (float*)d_out;

    // ws layout: u[N] | s[25N] | edges[NBLK*ECAP_G] int2 | gcnt[NBLK]
    //            | bar_cnt[25*16*32] | bar_master[25*32] | bar_gen[1]
    float* u     = (float*)d_ws;
    float* s     = u + N_NODES;
    int2*  edges = (int2*)(s + (size_t)MAX_POWER * N_NODES);  // byte off 5.2e6, 8B-aligned
    int*   gcnt       = (int*)(edges + (size_t)NBLK * ECAP_G);
    int*   bar_cnt    = gcnt + NBLK;
    int*   bar_master = bar_cnt + MAX_POWER * BAR_LINES * LSTRIDE;
    int*   bar_gen    = bar_master + MAX_POWER * LSTRIDE;

    // zero control area (gcnt + all barrier state) in one memset
    size_t ctrl_ints = (size_t)NBLK + MAX_POWER * BAR_LINES * LSTRIDE
                     + MAX_POWER * LSTRIDE + 1;
    hipMemsetAsync(gcnt, 0, ctrl_ints * sizeof(int), stream);

    // bucket partition (fixed-stride slots)
    partition_kernel<<<NPART, 256, 0, stream>>>(
        gso_rows, gso_cols, gso_vals, gcnt, edges, N_EDGES);

    // fused persistent chain
    int n_nodes = N_NODES;
    void* args[] = { (void*)&gcnt, (void*)&edges, (void*)&x, (void*)&coeff,
                     (void*)&u, (void*)&s, (void*)&y,
                     (void*)&bar_cnt, (void*)&bar_master, (void*)&bar_gen,
                     (void*)&n_nodes };
    hipLaunchCooperativeKernel((void*)chain_kernel, dim3(NBLK), dim3(512),
                               args, 0, stream);
}

// Round 10
// 410.975 us; speedup vs baseline: 6.2402x; 1.0335x over previous
//
#include <hip/hip_runtime.h>
#include <hip/hip_bf16.h>

#define N_NODES 50000
#define N_EDGES 1600000
#define F_IN    128
#define F_OUT   8
#define K_TAPS  4
#define MAX_POWER 25     // F_OUT*(K_TAPS-1)+1

#define NBLK    256      // chain blocks (1 per CU)
#define RPB     196      // rows per block (256*196 = 50176 >= 50000)
#define CHUNK   4096     // edges per partition block
#define NPART   391      // ceil(N_EDGES / CHUNK)
#define ECAP_G  8192     // global per-bucket slot stride (mean 6272)
#define ECAP_L  6912     // LDS edge-cache capacity (mean 6272, +14 sigma)
#define CSB     800      // col-sort buckets (col>>6 < 782), padded

#define FSTRIDE 16       // ints per flag line (64 B)

__device__ inline int wave_incl_scan(int v, int lane) {
    #pragma unroll
    for (int off = 1; off < 64; off <<= 1) {
        int t = __shfl_up(v, off, 64);
        if (lane >= off) v += t;
    }
    return v;
}

// sc1 store: to L3 (coherence point), bypassing non-coherent per-XCD L2.
__device__ inline void st_coh(float* p, float v) {
    __hip_atomic_store(p, v, __ATOMIC_RELAXED, __HIP_MEMORY_SCOPE_AGENT);
}

// ---------------------------------------------------------------------------
// Partition edges into fixed-stride bucket slots (bucket = row / RPB).
// LDS staging -> semi-coalesced run writes. Payload: ((row%RPB)<<16)|col, val.
// ---------------------------------------------------------------------------
__global__ void partition_kernel(const int* __restrict__ rows,
                                 const int* __restrict__ cols,
                                 const float* __restrict__ vals,
                                 int* __restrict__ gcnt,
                                 int2* __restrict__ edges, int n_edges) {
    __shared__ int lhist[NBLK];
    __shared__ int lcur[NBLK];
    __shared__ int lbase[NBLK];
    __shared__ int2 stage[CHUNK];
    __shared__ unsigned char sbkt[CHUNK];
    __shared__ int wsum[4];
    int tid = threadIdx.x;
    int base = blockIdx.x * CHUNK;
    int cend = min(base + CHUNK, n_edges);

    lhist[tid] = 0;
    __syncthreads();
    for (int i = base + tid; i < cend; i += 256)
        atomicAdd(&lhist[rows[i] / RPB], 1);
    __syncthreads();

    int lane = tid & 63, wid = tid >> 6;
    int h = lhist[tid];
    int incl = wave_incl_scan(h, lane);
    if (lane == 63) wsum[wid] = incl;
    __syncthreads();
    int woff = 0;
    for (int w = 0; w < wid; ++w) woff += wsum[w];
    int excl = woff + incl - h;
    lcur[tid] = excl;
    if (h) {
        int g = atomicAdd(&gcnt[tid], h);
        lbase[tid] = tid * ECAP_G + g - excl;
    }
    __syncthreads();

    for (int i = base + tid; i < cend; i += 256) {
        int r = rows[i], c = cols[i];
        float v = vals[i];
        int b = r / RPB;
        int pos = atomicAdd(&lcur[b], 1);
        stage[pos] = make_int2(((r - b * RPB) << 16) | c, __float_as_int(v));
        sbkt[pos] = (unsigned char)b;
    }
    __syncthreads();

    int cn = cend - base;
    for (int i = tid; i < cn; i += 256) {
        int b = sbkt[i];
        int o = lbase[b] + i;
        if (o - b * ECAP_G < ECAP_G)
            edges[o] = stage[i];
    }
}

// ---------------------------------------------------------------------------
// Flat distributed-poll barrier: block b sc1-stores monotone gen to its flag;
// threads 0..NBLK-1 each poll one flag. No serialized RMW chains, no fences.
// __syncthreads() before the store drains vmcnt(0) => prior sc1 stores acked.
// ---------------------------------------------------------------------------
__device__ inline void gbar(int gen, int* __restrict__ flags) {
    __syncthreads();
    if (threadIdx.x == 0)
        __hip_atomic_store(&flags[blockIdx.x * FSTRIDE], gen,
                           __ATOMIC_RELAXED, __HIP_MEMORY_SCOPE_AGENT);
    if (threadIdx.x < NBLK) {
        while (__hip_atomic_load(&flags[threadIdx.x * FSTRIDE],
                                 __ATOMIC_RELAXED, __HIP_MEMORY_SCOPE_AGENT) < gen)
            __builtin_amdgcn_s_sleep(2);
    }
    __syncthreads();
}

// ---------------------------------------------------------------------------
// Persistent chain: rowsum + 25 SpMV hops + y-fold. 256 blocks x 512 threads.
// Prologue counting-sorts the block's edges by col>>6 (halves gather TA work).
// Fresh dst buffer per hop => plain cached reads; sc1 writes to L3.
// ---------------------------------------------------------------------------
__global__ __launch_bounds__(512, 1)
void chain_kernel(const int* __restrict__ gcnt,
                  const int2* __restrict__ edges,
                  const float* __restrict__ x,
                  const float* __restrict__ coeff,
                  float* __restrict__ u,
                  float* __restrict__ s,          // 25 * N_NODES
                  float* __restrict__ y,
                  int* __restrict__ flags,
                  int n_nodes) {
    __shared__ int2  esort[ECAP_L];
    __shared__ int   chist[CSB];
    __shared__ int   ccur[CSB];
    __shared__ int   wsum8[8];
    __shared__ float acc[RPB];
    __shared__ float yacc[RPB * F_OUT];
    __shared__ float lcoeff[F_OUT * K_TAPS];

    int tid = threadIdx.x;
    int b = blockIdx.x;

    if (tid < RPB) acc[tid] = 0.f;
    for (int j = tid; j < RPB * F_OUT; j += 512) yacc[j] = 0.f;
    if (tid < F_OUT * K_TAPS) lcoeff[tid] = coeff[tid];

    int cnt = min(gcnt[b], ECAP_G);
    int cntl = min(cnt, ECAP_L);
    const int2* eb = edges + (size_t)b * ECAP_G;

    // --- prologue: counting-sort this bucket's edges by col>>6 into LDS ---
    for (int i = tid; i < CSB; i += 512) chist[i] = 0;
    __syncthreads();
    if (cnt <= ECAP_L) {
        for (int i = tid; i < cnt; i += 512) {
            int2 e = eb[i];
            atomicAdd(&chist[(e.x & 0xFFFF) >> 6], 1);
        }
        __syncthreads();
        int lane = tid & 63, wid = tid >> 6;
        int b0 = 2 * tid;
        int h0 = (b0 < CSB) ? chist[b0] : 0;
        int h1 = (b0 + 1 < CSB) ? chist[b0 + 1] : 0;
        int ps = h0 + h1;
        int incl = wave_incl_scan(ps, lane);
        if (lane == 63) wsum8[wid] = incl;
        __syncthreads();
        int woff = 0;
        for (int w = 0; w < wid; ++w) woff += wsum8[w];
        int ex = woff + incl - ps;
        if (b0 < CSB) ccur[b0] = ex;
        if (b0 + 1 < CSB) ccur[b0 + 1] = ex + h0;
        __syncthreads();
        for (int i = tid; i < cnt; i += 512) {
            int2 e = eb[i];
            int pos = atomicAdd(&ccur[(e.x & 0xFFFF) >> 6], 1);
            esort[pos] = e;
        }
    } else {
        for (int i = tid; i < cntl; i += 512) esort[i] = eb[i];  // fallback, unsorted
    }

    // --- rowsum: u[n] = sum_f x[n,f]; sc1 store so hop 0 reads fresh ---
    {
        int lane = tid & 63;
        int wave = (b * 512 + tid) >> 6;
        int n_waves = NBLK * 8;
        for (int node = wave; node < n_nodes; node += n_waves) {
            const float2* xp = (const float2*)(x + (size_t)node * F_IN);
            float2 v = xp[lane];
            float sm = v.x + v.y;
            #pragma unroll
            for (int off = 32; off > 0; off >>= 1)
                sm += __shfl_down(sm, off, 64);
            if (lane == 0) st_coh(&u[node], sm);
        }
    }
    gbar(1, flags);

    for (int p = 0; p < MAX_POWER; ++p) {
        const float* __restrict__ src = (p == 0) ? u : s + (size_t)(p - 1) * n_nodes;
        float* dst = s + (size_t)p * n_nodes;

        // 4-way unrolled gather (sorted cols => ~2 lanes/line coalescing)
        int i = tid;
        for (; i + 3 * 512 < cntl; i += 4 * 512) {
            int2 e0 = esort[i];
            int2 e1 = esort[i + 512];
            int2 e2 = esort[i + 1024];
            int2 e3 = esort[i + 1536];
            float v0 = src[e0.x & 0xFFFF];
            float v1 = src[e1.x & 0xFFFF];
            float v2 = src[e2.x & 0xFFFF];
            float v3 = src[e3.x & 0xFFFF];
            atomicAdd(&acc[e0.x >> 16], __int_as_float(e0.y) * v0);
            atomicAdd(&acc[e1.x >> 16], __int_as_float(e1.y) * v1);
            atomicAdd(&acc[e2.x >> 16], __int_as_float(e2.y) * v2);
            atomicAdd(&acc[e3.x >> 16], __int_as_float(e3.y) * v3);
        }
        for (; i < cntl; i += 512) {
            int2 ev = esort[i];
            atomicAdd(&acc[ev.x >> 16], __int_as_float(ev.y) * src[ev.x & 0xFFFF]);
        }
        for (int k = ECAP_L + tid; k < cnt; k += 512) {   // overflow (never for seed 0)
            int2 ev = eb[k];
            atomicAdd(&acc[ev.x >> 16], __int_as_float(ev.y) * src[ev.x & 0xFFFF]);
        }
        __syncthreads();

        if (tid < RPB) {
            int row = b * RPB + tid;
            float val = acc[tid];
            acc[tid] = 0.f;
            if (p < MAX_POWER - 1 && row < n_nodes) st_coh(&dst[row], val);
            #pragma unroll
            for (int o = 0; o < F_OUT; ++o) {
                int k = p - (K_TAPS - 1) * o;        // tap index for output o
                if (k >= 0 && k < K_TAPS)
                    yacc[tid * F_OUT + o] += lcoeff[o * K_TAPS + k] * val;
            }
        }
        if (p < MAX_POWER - 1)
            gbar(p + 2, flags);
    }

    __syncthreads();
    for (int j = tid; j < RPB * F_OUT; j += 512) {
        int row = b * RPB + (j >> 3);
        if (row < n_nodes) y[(size_t)row * F_OUT + (j & 7)] = yacc[j];
    }
}

extern "C" void kernel_launch(void* const* d_in, const int* in_sizes, int n_in,
                              void* d_out, int out_size, void* d_ws, size_t ws_size,
                              hipStream_t stream) {
    const float* x        = (const float*)d_in[0];
    const int*   gso_rows = (const int*)d_in[1];
    const int*   gso_cols = (const int*)d_in[2];
    const float* gso_vals = (const float*)d_in[3];
    const float* coeff    = (const float*)d_in[4];
    float* y = (float*)d_out;

    // ws layout: u[N] | s[25N] | edges[NBLK*ECAP_G] int2 | gcnt[NBLK]
    //            | flags[NBLK*FSTRIDE]
    float* u     = (float*)d_ws;
    float* s     = u + N_NODES;
    int2*  edges = (int2*)(s + (size_t)MAX_POWER * N_NODES);  // 8B-aligned
    int*   gcnt  = (int*)(edges + (size_t)NBLK * ECAP_G);
    int*   flags = gcnt + NBLK;

    // zero control area (gcnt + flags) in one memset
    size_t ctrl_ints = (size_t)NBLK + (size_t)NBLK * FSTRIDE;
    hipMemsetAsync(gcnt, 0, ctrl_ints * sizeof(int), stream);

    // bucket partition (fixed-stride slots)
    partition_kernel<<<NPART, 256, 0, stream>>>(
        gso_rows, gso_cols, gso_vals, gcnt, edges, N_EDGES);

    // fused persistent chain
    int n_nodes = N_NODES;
    void* args[] = { (void*)&gcnt, (void*)&edges, (void*)&x, (void*)&coeff,
                     (void*)&u, (void*)&s, (void*)&y, (void*)&flags,
                     (void*)&n_nodes };
    hipLaunchCooperativeKernel((void*)chain_kernel, dim3(NBLK), dim3(512),
                               args, 0, stream);
}